// Round 6
// baseline (2488.116 us; speedup 1.0000x reference)
//
#include <hip/hip_runtime.h>
#include <hip/hip_bf16.h>
#include <math.h>

typedef unsigned short u16;
typedef __attribute__((ext_vector_type(8))) short bf16x8;
typedef __attribute__((ext_vector_type(4))) float f32x4;
typedef __attribute__((ext_vector_type(16))) float f32x16;

#define IN_CH   256
#define STATE   384
#define OUT_SEQ 32
#define B_SZ    8
#define SEQ     512
#define M_ROWS  4096
#define NJ      768   // 2*STATE

// ---------------- workspace layout (bytes) ----------------
// B_U region: U fp32 [4096][768] (12.58MB) for gemm1/emit, then reused as
// 8 GEMM2 fp32 partials (8*4096*256*4 = 33.55MB). Sized for the max.
static constexpr size_t B_U   = 0;
static constexpr size_t B_Z   = B_U  + 8*(size_t)M_ROWS*IN_CH*4;     // 33.55MB
static constexpr size_t B_XA  = B_Z  + 3*(size_t)M_ROWS*NJ*2;
static constexpr size_t B_XB  = B_XA + 3*(size_t)M_ROWS*IN_CH*2;
static constexpr size_t B_WB  = B_XB + 3*(size_t)M_ROWS*IN_CH*2;
static constexpr size_t B_WC  = B_WB + 3*(size_t)NJ*IN_CH*2;
static constexpr size_t B_WD  = B_WC + 3*(size_t)IN_CH*NJ*2;
static constexpr size_t B_LAM = B_WD + 3*(size_t)IN_CH*IN_CH*2;      // lam, lam64
static constexpr size_t B_HC  = B_LAM + 2*768*4;                     // Hc0, Hc1
static constexpr size_t B_CAR = B_HC  + 2*(size_t)B_SZ*NJ*4;         // carries

// ---------------- helpers ----------------
__device__ __forceinline__ u16 f2b(float v) {
    __hip_bfloat16 h = __float2bfloat16(v);
    return *(u16*)&h;
}
__device__ __forceinline__ float b2f(u16 u) {
    __hip_bfloat16 h = *(__hip_bfloat16*)&u;
    return __bfloat162float(h);
}
__device__ __forceinline__ void split3(float v, u16& a, u16& b, u16& c) {
    a = f2b(v);  float r1 = v  - b2f(a);
    b = f2b(r1); float r2 = r1 - b2f(b);
    c = f2b(r2);
}
__device__ __forceinline__ void gload_lds16(const void* g, void* l) {
    __builtin_amdgcn_global_load_lds(
        (const __attribute__((address_space(1))) void*)g,
        (__attribute__((address_space(3))) void*)l, 16, 0, 0);
}

// ---------------- prep kernels ----------------
__global__ void prep_lam_hc(const float* __restrict__ nu_log,
                            const float* __restrict__ th_log,
                            float* __restrict__ lam, float* __restrict__ lam64,
                            float* __restrict__ hc0) {
    int n = threadIdx.x;
    if (n < STATE) {
        float lm = expf(-expf(nu_log[n]));
        float th = expf(th_log[n]);
        float ar = lm * cosf(th), ai = lm * sinf(th);
        lam[2*n] = ar; lam[2*n+1] = ai;
        float pr = ar, pi = ai;
#pragma unroll
        for (int i = 0; i < 6; ++i) {   // lambda^64
            float nr = pr*pr - pi*pi, ni = 2.f*pr*pi;
            pr = nr; pi = ni;
        }
        lam64[2*n] = pr; lam64[2*n+1] = pi;
    }
    for (int i = threadIdx.x; i < B_SZ*NJ; i += blockDim.x) hc0[i] = 0.f;
}

// WB planes: W[p][j][c] = split_p(gamma_n * B_{re/im}[n][c]), j=2n+f, [768][256]
__global__ void prep_wb(const float* __restrict__ B_re, const float* __restrict__ B_im,
                        const float* __restrict__ gamma_log, u16* __restrict__ W) {
    int idx = blockIdx.x*blockDim.x + threadIdx.x;   // < 768*256
    int j = idx >> 8, c = idx & 255, n = j >> 1;
    float g = expf(gamma_log[n]);
    float v = g * ((j & 1) ? B_im[n*IN_CH + c] : B_re[n*IN_CH + c]);
    u16 a,b,cc; split3(v,a,b,cc);
    W[idx] = a; W[idx + NJ*IN_CH] = b; W[idx + 2*NJ*IN_CH] = cc;
}

__global__ void prep_wcd(const float* __restrict__ C_re, const float* __restrict__ C_im,
                         const float* __restrict__ D,
                         u16* __restrict__ WC, u16* __restrict__ WD) {
    int idx = blockIdx.x*blockDim.x + threadIdx.x;
    if (idx < IN_CH*NJ) {
        int o = idx / NJ, j = idx % NJ, n = j >> 1;
        float v = (j & 1) ? -C_im[o*STATE + n] : C_re[o*STATE + n];
        u16 a,b,c; split3(v,a,b,c);
        WC[idx] = a; WC[idx + IN_CH*NJ] = b; WC[idx + 2*IN_CH*NJ] = c;
    } else {
        int k = idx - IN_CH*NJ;
        float v = D[k];
        u16 a,b,c; split3(v,a,b,c);
        WD[k] = a; WD[k + IN_CH*IN_CH] = b; WD[k + 2*IN_CH*IN_CH] = c;
    }
}

__global__ void prep_x(const float* __restrict__ x,
                       u16* __restrict__ X1, u16* __restrict__ X2, u16* __restrict__ X3) {
    int idx = blockIdx.x*blockDim.x + threadIdx.x;
    u16 a,b,c; split3(x[idx],a,b,c);
    X1[idx] = a; X2[idx] = b; X3[idx] = c;
}

// product order for bf16x3 (large terms first)
#define PI0 0
#define PJ0 0
__device__ __constant__ const int cPI[6] = {0,0,1,0,1,2};
__device__ __constant__ const int cPJ[6] = {0,1,0,2,1,0};

// ---------------- GEMM1: U = sum_6 X_pi * WB_pj^T, + fused chunk-carry scan ----
// 64x64 tile, 4 waves (2x2), 32x32x16 MFMA, A-only LDS staging, B in registers.
struct G1P { const u16* A[3]; };

__global__ __launch_bounds__(256, 2)
void gemm1_k(G1P ga, const u16* __restrict__ WBp, float* __restrict__ Uout,
             const float* __restrict__ lam, float2* __restrict__ carry) {
    __shared__ __align__(16) char smem[24576];   // 2 x 12KB (A dbuf)
    const int tid = threadIdx.x, lane = tid & 63, w = tid >> 6;
    const int wr = w & 1, wc = w >> 1;
    const int m0 = blockIdx.x*64, n0 = blockIdx.y*64;
    const int hi5 = lane >> 5, lo5 = lane & 31;

    f32x16 acc;
#pragma unroll
    for (int i = 0; i < 16; ++i) acc[i] = 0.f;

    // B fragments in registers: one 128-K window at a time
    const u16* Bbase = WBp + (size_t)(n0 + wc*32 + lo5)*IN_CH;
    bf16x8 bwin[3][4][2];
    auto loadB = [&](int cw) {
#pragma unroll
        for (int p = 0; p < 3; ++p)
#pragma unroll
            for (int t = 0; t < 4; ++t)
#pragma unroll
                for (int h = 0; h < 2; ++h)
                    bwin[p][t][h] = *(const bf16x8*)(Bbase + (size_t)p*(NJ*IN_CH)
                                                     + cw*128 + t*32 + (2*h + hi5)*8);
    };

    auto stageA = [&](int s, int buf) {
        int kg = s*32;
        char* L = smem + buf*12288;
#pragma unroll
        for (int r = 0; r < 3; ++r) {            // 768 chunks of 16B
            int q = tid + r*256;
            int p = q >> 8, c = q & 255, o = c >> 6, row = c & 63;
            gload_lds16(ga.A[p] + (size_t)(m0 + row)*IN_CH + kg + o*8,
                        L + (size_t)q*16);
        }
    };

    stageA(0, 0);
    loadB(0);
    __syncthreads();
    int cur = 0;
#pragma unroll
    for (int s = 0; s < 8; ++s) {
        if (s == 4) loadB(1);
        if (s + 1 < 8) stageA(s + 1, cur ^ 1);
        const char* L = smem + cur*12288;
        bf16x8 av[3][2];
#pragma unroll
        for (int p = 0; p < 3; ++p)
#pragma unroll
            for (int h = 0; h < 2; ++h)
                av[p][h] = *(const bf16x8*)(L + p*4096 + (2*h + hi5)*1024
                                            + (wr*32 + lo5)*16);
        const int tw = s & 3;
#pragma unroll
        for (int t6 = 0; t6 < 6; ++t6)
#pragma unroll
            for (int h = 0; h < 2; ++h)
                acc = __builtin_amdgcn_mfma_f32_32x32x16_bf16(
                    av[cPI[t6]][h], bwin[cPJ[t6]][tw][h], acc, 0, 0, 0);
        __syncthreads();
        cur ^= 1;
    }

    // epilogue: U to global + LDS tile; D layout col=lane&31, row=(reg&3)+8*(reg>>2)+4*hi5
    float* Ls = (float*)smem;                     // [64][64] fp32 = 16KB
#pragma unroll
    for (int reg = 0; reg < 16; ++reg) {
        int rl = wr*32 + (reg & 3) + 8*(reg >> 2) + 4*hi5;
        int cl = wc*32 + lo5;
        float v = acc[reg];
        Uout[(size_t)(m0 + rl)*NJ + n0 + cl] = v;
        Ls[rl*64 + cl] = v;
    }
    __syncthreads();

    // fused chunk carry: 32 threads, one per state in this n-slice, 64-step local scan
    if (tid < 32) {
        int b = m0 >> 9, ch = (m0 >> 6) & 7;
        int n = (n0 >> 1) + tid;
        float lre = lam[2*n], lim = lam[2*n+1];
        float hr = 0.f, hm = 0.f;
        const float2* L2 = (const float2*)smem;   // [64][32] float2
        float2 pf[8];
#pragma unroll
        for (int p = 0; p < 8; ++p) pf[p] = L2[p*32 + tid];
        for (int s0 = 0; s0 < 64; s0 += 8) {
#pragma unroll
            for (int p = 0; p < 8; ++p) {
                int s = s0 + p;
                float ur = pf[p].x, ui = pf[p].y;
                if (s + 8 < 64) pf[p] = L2[(s + 8)*32 + tid];
                float nr = fmaf(lre, hr, fmaf(-lim, hm, ur));
                float nm = fmaf(lre, hm, fmaf( lim, hr, ui));
                hr = nr; hm = nm;
            }
        }
        carry[(size_t)(b*8 + ch)*STATE + n] = make_float2(hr, hm);
    }
}

// ---------------- scan emit: prefix from carries, emit Z splits ----------------
__global__ __launch_bounds__(64)
void scan_emit(const float* __restrict__ Uf,
               u16* __restrict__ Z1, u16* __restrict__ Z2, u16* __restrict__ Z3,
               const float* __restrict__ lam, const float* __restrict__ lam64,
               const float2* __restrict__ carry,
               const float2* __restrict__ HcIn, float2* __restrict__ HcOut) {
    int bx = blockIdx.x;
    int b = bx / 48, rem = bx % 48, g = rem >> 3, c = rem & 7;
    int n = g*64 + threadIdx.x;
    float lre = lam[2*n], lim = lam[2*n+1];
    float p64r = lam64[2*n], p64i = lam64[2*n+1];
    float2 h = HcIn[(size_t)b*STATE + n];
    for (int j = 0; j < c; ++j) {
        float2 cj = carry[(size_t)(b*8 + j)*STATE + n];
        float nr = fmaf(p64r, h.x, fmaf(-p64i, h.y, cj.x));
        float ni = fmaf(p64r, h.y, fmaf( p64i, h.x, cj.y));
        h.x = nr; h.y = ni;
    }
    const float2* U2 = (const float2*)Uf + ((size_t)(b*SEQ + c*64))*STATE + n;
    size_t zb = (size_t)(b*SEQ + c*64)*NJ + 2*n;
    float2 buf[16];
#pragma unroll
    for (int p = 0; p < 16; ++p) buf[p] = U2[(size_t)p*STATE];
    for (int s0 = 0; s0 < 64; s0 += 16) {
#pragma unroll
        for (int p = 0; p < 16; ++p) {
            int s = s0 + p;
            float ur = buf[p].x, ui = buf[p].y;
            if (s + 16 < 64) buf[p] = U2[(size_t)(s+16)*STATE];
            float nr = fmaf(lre, h.x, fmaf(-lim, h.y, ur));
            float ni = fmaf(lre, h.y, fmaf( lim, h.x, ui));
            h.x = nr; h.y = ni;
            u16 a1,a2,a3, c1,c2,c3;
            split3(nr, a1,a2,a3);
            split3(ni, c1,c2,c3);
            size_t zo = zb + (size_t)s*NJ;
            ushort2 t;
            t.x = a1; t.y = c1; *(ushort2*)(Z1 + zo) = t;
            t.x = a2; t.y = c2; *(ushort2*)(Z2 + zo) = t;
            t.x = a3; t.y = c3; *(ushort2*)(Z3 + zo) = t;
        }
    }
    if (c == 7) HcOut[(size_t)b*STATE + n] = h;
}

// ---------------- GEMM2: z=8 uniform 128-K split; 128x64 tile; B in regs ------
// z 0..5: Z planes k-slice [z*128, z*128+128) vs WC; z 6..7: X planes vs WD.
struct G2P { const u16* Z[3]; const u16* X[3]; const u16* WC; const u16* WD; float* P; };

__global__ __launch_bounds__(256, 2)
void gemm2_k(G2P g) {
    __shared__ __align__(16) char smem[49152];   // 2 x 24KB (A dbuf)
    const int tid = threadIdx.x, lane = tid & 63, w = tid >> 6;
    const int wr = w & 1, wc = w >> 1;
    const int m0 = blockIdx.x*128, n0 = blockIdx.y*64;
    const int z = blockIdx.z;
    const int hi5 = lane >> 5, lo5 = lane & 31;

    const u16* Ap[3]; const u16* Bp; int sA, sB, kg0; size_t pBs;
    if (z < 6) {
        Ap[0]=g.Z[0]; Ap[1]=g.Z[1]; Ap[2]=g.Z[2];
        sA = NJ; kg0 = z*128; Bp = g.WC; sB = NJ; pBs = (size_t)IN_CH*NJ;
    } else {
        Ap[0]=g.X[0]; Ap[1]=g.X[1]; Ap[2]=g.X[2];
        sA = IN_CH; kg0 = (z - 6)*128; Bp = g.WD; sB = IN_CH; pBs = (size_t)IN_CH*IN_CH;
    }

    f32x16 acc[2];
#pragma unroll
    for (int f = 0; f < 2; ++f)
#pragma unroll
        for (int i = 0; i < 16; ++i) acc[f][i] = 0.f;

    // B fragments in registers (whole 128-K slice)
    const u16* Bbase = Bp + (size_t)(n0 + wc*32 + lo5)*sB + kg0;
    bf16x8 bwin[3][4][2];
#pragma unroll
    for (int p = 0; p < 3; ++p)
#pragma unroll
        for (int t = 0; t < 4; ++t)
#pragma unroll
            for (int h = 0; h < 2; ++h)
                bwin[p][t][h] = *(const bf16x8*)(Bbase + p*pBs + t*32 + (2*h + hi5)*8);

    auto stageA = [&](int t, int buf) {
        int kg = kg0 + t*32;
        char* L = smem + buf*24576;
#pragma unroll
        for (int r = 0; r < 6; ++r) {            // 1536 chunks of 16B
            int q = tid + r*256;
            int p = q >> 9, c = q & 511, o = c >> 7, row = c & 127;
            gload_lds16(Ap[p] + (size_t)(m0 + row)*sA + kg + o*8,
                        L + (size_t)q*16);
        }
    };

    stageA(0, 0);
    __syncthreads();
    int cur = 0;
#pragma unroll
    for (int t = 0; t < 4; ++t) {
        if (t + 1 < 4) stageA(t + 1, cur ^ 1);
        const char* L = smem + cur*24576;
        bf16x8 av[3][2][2];
#pragma unroll
        for (int p = 0; p < 3; ++p)
#pragma unroll
            for (int f = 0; f < 2; ++f)
#pragma unroll
                for (int h = 0; h < 2; ++h)
                    av[p][f][h] = *(const bf16x8*)(L + p*8192 + (2*h + hi5)*2048
                                                   + (wr*64 + f*32 + lo5)*16);
#pragma unroll
        for (int t6 = 0; t6 < 6; ++t6)
#pragma unroll
            for (int f = 0; f < 2; ++f)
#pragma unroll
                for (int h = 0; h < 2; ++h)
                    acc[f] = __builtin_amdgcn_mfma_f32_32x32x16_bf16(
                        av[cPI[t6]][f][h], bwin[cPJ[t6]][t][h], acc[f], 0, 0, 0);
        __syncthreads();
        cur ^= 1;
    }

    // epilogue: fp32 partial plane z
    float* P = g.P + (size_t)z*M_ROWS*IN_CH;
#pragma unroll
    for (int f = 0; f < 2; ++f)
#pragma unroll
        for (int reg = 0; reg < 16; ++reg) {
            int row = m0 + wr*64 + f*32 + (reg & 3) + 8*(reg >> 2) + 4*hi5;
            int col = n0 + wc*32 + lo5;
            P[(size_t)row*IN_CH + col] = acc[f][reg];
        }
}

// ---------------- combine 8 partials -> split3 planes + out row ----------------
__global__ __launch_bounds__(256)
void combine_k(const float* __restrict__ P,
               u16* __restrict__ O1, u16* __restrict__ O2, u16* __restrict__ O3,
               float* __restrict__ outp, int iter) {
    int idx = blockIdx.x*256 + threadIdx.x;     // 0..262143 (f32x4 units)
    const f32x4* P4 = (const f32x4*)P;
    f32x4 v = P4[idx];
#pragma unroll
    for (int z = 1; z < 8; ++z) v = v + P4[idx + (size_t)z*262144];
    ushort4 o1, o2, o3;
    u16 a,b,c;
    split3(v[0],a,b,c); o1.x=a; o2.x=b; o3.x=c;
    split3(v[1],a,b,c); o1.y=a; o2.y=b; o3.y=c;
    split3(v[2],a,b,c); o1.z=a; o2.z=b; o3.z=c;
    split3(v[3],a,b,c); o1.w=a; o2.w=b; o3.w=c;
    ((ushort4*)O1)[idx] = o1;
    ((ushort4*)O2)[idx] = o2;
    ((ushort4*)O3)[idx] = o3;
    int row = idx >> 6;
    if ((row & (SEQ-1)) == SEQ-1) {
        int col = (idx & 63) << 2;
        *(float4*)&outp[(size_t)((row >> 9)*OUT_SEQ + iter)*IN_CH + col] =
            make_float4(v[0], v[1], v[2], v[3]);
    }
}

// ---------------- launch ----------------
extern "C" void kernel_launch(void* const* d_in, const int* in_sizes, int n_in,
                              void* d_out, int out_size, void* d_ws, size_t ws_size,
                              hipStream_t stream) {
    const float* x_in      = (const float*)d_in[0];
    const float* nu_log    = (const float*)d_in[1];
    const float* theta_log = (const float*)d_in[2];
    const float* gamma_log = (const float*)d_in[3];
    const float* B_re      = (const float*)d_in[4];
    const float* B_im      = (const float*)d_in[5];
    const float* C_re      = (const float*)d_in[6];
    const float* C_im      = (const float*)d_in[7];
    const float* D         = (const float*)d_in[8];
    float* out = (float*)d_out;

    char* ws = (char*)d_ws;
    float* U   = (float*)(ws + B_U);     // first 12.58MB = U; full 33.55MB = partials
    u16* Z1 = (u16*)(ws + B_Z);
    u16* Z2 = Z1 + (size_t)M_ROWS*NJ;
    u16* Z3 = Z2 + (size_t)M_ROWS*NJ;
    u16* XA1 = (u16*)(ws + B_XA);
    u16* XA2 = XA1 + (size_t)M_ROWS*IN_CH;
    u16* XA3 = XA2 + (size_t)M_ROWS*IN_CH;
    u16* XB1 = (u16*)(ws + B_XB);
    u16* XB2 = XB1 + (size_t)M_ROWS*IN_CH;
    u16* XB3 = XB2 + (size_t)M_ROWS*IN_CH;
    u16* WB  = (u16*)(ws + B_WB);
    u16* WCt = (u16*)(ws + B_WC);
    u16* WDt = (u16*)(ws + B_WD);
    float* lam   = (float*)(ws + B_LAM);
    float* lam64 = lam + 768;
    float2* Hc0  = (float2*)(ws + B_HC);
    float2* Hc1  = Hc0 + (size_t)B_SZ*STATE;
    float2* carry = (float2*)(ws + B_CAR);

    prep_lam_hc<<<1, 384, 0, stream>>>(nu_log, theta_log, lam, lam64, (float*)Hc0);
    prep_wb<<<(NJ*IN_CH)/256, 256, 0, stream>>>(B_re, B_im, gamma_log, WB);
    prep_wcd<<<(IN_CH*NJ + IN_CH*IN_CH)/256, 256, 0, stream>>>(C_re, C_im, D, WCt, WDt);
    prep_x<<<(M_ROWS*IN_CH)/256, 256, 0, stream>>>(x_in, XA1, XA2, XA3);

    for (int it = 0; it < OUT_SEQ; ++it) {
        u16* Xc[3]; u16* Xn[3];
        if (it & 1) { Xc[0]=XB1; Xc[1]=XB2; Xc[2]=XB3; Xn[0]=XA1; Xn[1]=XA2; Xn[2]=XA3; }
        else        { Xc[0]=XA1; Xc[1]=XA2; Xc[2]=XA3; Xn[0]=XB1; Xn[1]=XB2; Xn[2]=XB3; }
        float2* Hin  = (it & 1) ? Hc1 : Hc0;
        float2* Hout = (it & 1) ? Hc0 : Hc1;

        // GEMM1 + fused chunk-carries
        G1P g1;
        for (int p = 0; p < 3; ++p) g1.A[p] = Xc[p];
        gemm1_k<<<dim3(M_ROWS/64, NJ/64), 256, 0, stream>>>(g1, WB, U, lam, carry);

        // scan emit (prefix from carries)
        scan_emit<<<384, 64, 0, stream>>>(U, Z1, Z2, Z3, lam, lam64, carry, Hin, Hout);

        // GEMM2: z=8 uniform 128-K split partials
        G2P g2;
        g2.Z[0]=Z1; g2.Z[1]=Z2; g2.Z[2]=Z3;
        g2.X[0]=Xc[0]; g2.X[1]=Xc[1]; g2.X[2]=Xc[2];
        g2.WC = WCt; g2.WD = WDt; g2.P = U;
        gemm2_k<<<dim3(M_ROWS/128, IN_CH/64, 8), 256, 0, stream>>>(g2);

        // combine partials -> Xn splits + out row
        combine_k<<<1024, 256, 0, stream>>>(U, Xn[0], Xn[1], Xn[2], out, it);
    }
}

// Round 7
// 1915.767 us; speedup vs baseline: 1.2988x; 1.2988x over previous
//
#include <hip/hip_runtime.h>
#include <hip/hip_bf16.h>
#include <math.h>

typedef unsigned short u16;
typedef __attribute__((ext_vector_type(8))) short bf16x8;
typedef __attribute__((ext_vector_type(4))) float f32x4;
typedef __attribute__((ext_vector_type(16))) float f32x16;

#define IN_CH   256
#define STATE   384
#define OUT_SEQ 32
#define B_SZ    8
#define SEQ     512
#define M_ROWS  4096
#define NJ      768   // 2*STATE

// plane sizes (elements)
#define PS_WB  (NJ*IN_CH)      // 196608
#define PS_WC  (IN_CH*NJ)      // 196608
#define PS_WD  (IN_CH*IN_CH)   // 65536

// ---------------- workspace layout (bytes) ----------------
static constexpr size_t B_U   = 0;                                   // U / 8 partials
static constexpr size_t B_Z   = B_U  + 8*(size_t)M_ROWS*IN_CH*4;     // 33.55MB
static constexpr size_t B_XA  = B_Z  + 3*(size_t)M_ROWS*NJ*2;
static constexpr size_t B_XB  = B_XA + 3*(size_t)M_ROWS*IN_CH*2;
static constexpr size_t B_WB  = B_XB + 3*(size_t)M_ROWS*IN_CH*2;
static constexpr size_t B_WC  = B_WB + 3*(size_t)PS_WB*2;
static constexpr size_t B_WD  = B_WC + 3*(size_t)PS_WC*2;
static constexpr size_t B_LAM = B_WD + 3*(size_t)PS_WD*2;            // lam, lam64
static constexpr size_t B_HC  = B_LAM + 2*768*4;                     // Hc0, Hc1
static constexpr size_t B_CAR = B_HC  + 2*(size_t)B_SZ*NJ*4;         // carries

// ---------------- helpers ----------------
__device__ __forceinline__ u16 f2b(float v) {
    __hip_bfloat16 h = __float2bfloat16(v);
    return *(u16*)&h;
}
__device__ __forceinline__ float b2f(u16 u) {
    __hip_bfloat16 h = *(__hip_bfloat16*)&u;
    return __bfloat162float(h);
}
__device__ __forceinline__ void split3(float v, u16& a, u16& b, u16& c) {
    a = f2b(v);  float r1 = v  - b2f(a);
    b = f2b(r1); float r2 = r1 - b2f(b);
    c = f2b(r2);
}
__device__ __forceinline__ void gload_lds16(const void* g, void* l) {
    __builtin_amdgcn_global_load_lds(
        (const __attribute__((address_space(1))) void*)g,
        (__attribute__((address_space(3))) void*)l, 16, 0, 0);
}

// fragment-index decode: r (within one c32 block) -> (t32,h,hi5,lo5,e)
// chunk layout per t32: [h][hi5][lo5][e] = 1024 elements
__device__ __forceinline__ void frag_decode(int r, int& t32, int& h, int& hi5,
                                            int& lo5, int& e) {
    t32 = r >> 10; int r2 = r & 1023;
    h = r2 >> 9;   int r3 = r2 & 511;
    hi5 = r3 >> 8; int r4 = r3 & 255;
    lo5 = r4 >> 3; e = r4 & 7;
}

// ---------------- prep kernels ----------------
__global__ void prep_lam_hc(const float* __restrict__ nu_log,
                            const float* __restrict__ th_log,
                            float* __restrict__ lam, float* __restrict__ lam64,
                            float* __restrict__ hc0) {
    int n = threadIdx.x;
    if (n < STATE) {
        float lm = expf(-expf(nu_log[n]));
        float th = expf(th_log[n]);
        float ar = lm * cosf(th), ai = lm * sinf(th);
        lam[2*n] = ar; lam[2*n+1] = ai;
        float pr = ar, pi = ai;
#pragma unroll
        for (int i = 0; i < 6; ++i) {   // lambda^64
            float nr = pr*pr - pi*pi, ni = 2.f*pr*pi;
            pr = nr; pi = ni;
        }
        lam64[2*n] = pr; lam64[2*n+1] = pi;
    }
    for (int i = threadIdx.x; i < B_SZ*NJ; i += blockDim.x) hc0[i] = 0.f;
}

// WB fragment-ordered: Ncols=768 (j), K=256 (c). per-c32 block = 8192 elems, NT32=8.
__global__ void prep_wb(const float* __restrict__ B_re, const float* __restrict__ B_im,
                        const float* __restrict__ gamma_log, u16* __restrict__ W) {
    int idx = blockIdx.x*blockDim.x + threadIdx.x;   // < 196608
    int c32 = idx >> 13, r = idx & 8191;
    int t32,h,hi5,lo5,e; frag_decode(r, t32,h,hi5,lo5,e);
    int j = c32*32 + lo5;
    int k = t32*32 + (2*h + hi5)*8 + e;
    int n = j >> 1;
    float g = expf(gamma_log[n]);
    float v = g * ((j & 1) ? B_im[n*IN_CH + k] : B_re[n*IN_CH + k]);
    u16 a,b,cc; split3(v,a,b,cc);
    W[idx] = a; W[idx + PS_WB] = b; W[idx + 2*PS_WB] = cc;
}

// WC: Ncols=256 (o), K=768 (j): per-c32 block = 24576, NT32=24.
// WD: Ncols=256 (o), K=256 (c): per-c32 block = 8192,  NT32=8.
__global__ void prep_wcd(const float* __restrict__ C_re, const float* __restrict__ C_im,
                         const float* __restrict__ D,
                         u16* __restrict__ WC, u16* __restrict__ WD) {
    int idx = blockIdx.x*blockDim.x + threadIdx.x;   // < 196608 + 65536
    if (idx < PS_WC) {
        int c32 = idx / 24576, r = idx % 24576;
        int t32,h,hi5,lo5,e; frag_decode(r, t32,h,hi5,lo5,e);
        int o = c32*32 + lo5;
        int j = t32*32 + (2*h + hi5)*8 + e;
        int n = j >> 1;
        float v = (j & 1) ? -C_im[o*STATE + n] : C_re[o*STATE + n];
        u16 a,b,c; split3(v,a,b,c);
        WC[idx] = a; WC[idx + PS_WC] = b; WC[idx + 2*PS_WC] = c;
    } else {
        int q = idx - PS_WC;
        int c32 = q >> 13, r = q & 8191;
        int t32,h,hi5,lo5,e; frag_decode(r, t32,h,hi5,lo5,e);
        int o = c32*32 + lo5;
        int c = t32*32 + (2*h + hi5)*8 + e;
        float v = D[o*IN_CH + c];
        u16 a,b,cc; split3(v,a,b,cc);
        WD[q] = a; WD[q + PS_WD] = b; WD[q + 2*PS_WD] = cc;
    }
}

__global__ void prep_x(const float* __restrict__ x,
                       u16* __restrict__ X1, u16* __restrict__ X2, u16* __restrict__ X3) {
    int idx = blockIdx.x*blockDim.x + threadIdx.x;
    u16 a,b,c; split3(x[idx],a,b,c);
    X1[idx] = a; X2[idx] = b; X3[idx] = c;
}

// product order for bf16x3 (large terms first)
__device__ __constant__ const int cPI[6] = {0,0,1,0,1,2};
__device__ __constant__ const int cPJ[6] = {0,1,0,2,1,0};

// ---------------- GEMM1: U = sum_6 X_pi * WB_pj^T, + fused chunk-carry scan ----
// 64x64 tile, 4 waves (2x2), 32x32x16 MFMA, A-only LDS staging, B in regs
// (fragment-ordered coalesced loads).
struct G1P { const u16* A[3]; };

__global__ __launch_bounds__(256, 2)
void gemm1_k(G1P ga, const u16* __restrict__ WBp, float* __restrict__ Uout,
             const float* __restrict__ lam, float2* __restrict__ carry) {
    __shared__ __align__(16) char smem[24576];   // 2 x 12KB (A dbuf)
    const int tid = threadIdx.x, lane = tid & 63, w = tid >> 6;
    const int wr = w & 1, wc = w >> 1;
    const int m0 = blockIdx.x*64, n0 = blockIdx.y*64;
    const int hi5 = lane >> 5, lo5 = lane & 31;
    const int c32 = (n0 >> 5) + wc;

    f32x16 acc;
#pragma unroll
    for (int i = 0; i < 16; ++i) acc[i] = 0.f;

    // B fragments in registers: one 128-K window (4 t-steps) at a time
    bf16x8 bwin[3][4][2];
    auto loadB = [&](int cw) {
#pragma unroll
        for (int p = 0; p < 3; ++p)
#pragma unroll
            for (int t = 0; t < 4; ++t)
#pragma unroll
                for (int h = 0; h < 2; ++h)
                    bwin[p][t][h] = *(const bf16x8*)(WBp + (size_t)p*PS_WB
                        + ((((size_t)(c32*8 + cw*4 + t)*2 + h)*2 + hi5) << 8) + lo5*8);
    };

    auto stageA = [&](int s, int buf) {
        int kg = s*32;
        char* L = smem + buf*12288;
#pragma unroll
        for (int r = 0; r < 3; ++r) {            // 768 chunks of 16B
            int q = tid + r*256;
            int p = q >> 8, c = q & 255, o = c >> 6, row = c & 63;
            gload_lds16(ga.A[p] + (size_t)(m0 + row)*IN_CH + kg + o*8,
                        L + (size_t)q*16);
        }
    };

    stageA(0, 0);
    loadB(0);
    __syncthreads();
    int cur = 0;
#pragma unroll
    for (int s = 0; s < 8; ++s) {
        if (s == 4) loadB(1);
        if (s + 1 < 8) stageA(s + 1, cur ^ 1);
        const char* L = smem + cur*12288;
        bf16x8 av[3][2];
#pragma unroll
        for (int p = 0; p < 3; ++p)
#pragma unroll
            for (int h = 0; h < 2; ++h)
                av[p][h] = *(const bf16x8*)(L + p*4096 + (2*h + hi5)*1024
                                            + (wr*32 + lo5)*16);
        const int tw = s & 3;
#pragma unroll
        for (int t6 = 0; t6 < 6; ++t6)
#pragma unroll
            for (int h = 0; h < 2; ++h)
                acc = __builtin_amdgcn_mfma_f32_32x32x16_bf16(
                    av[cPI[t6]][h], bwin[cPJ[t6]][tw][h], acc, 0, 0, 0);
        __syncthreads();
        cur ^= 1;
    }

    // epilogue: U to global + LDS tile; D layout col=lane&31, row=(reg&3)+8*(reg>>2)+4*hi5
    float* Ls = (float*)smem;                     // [64][64] fp32 = 16KB
#pragma unroll
    for (int reg = 0; reg < 16; ++reg) {
        int rl = wr*32 + (reg & 3) + 8*(reg >> 2) + 4*hi5;
        int cl = wc*32 + lo5;
        float v = acc[reg];
        Uout[(size_t)(m0 + rl)*NJ + n0 + cl] = v;
        Ls[rl*64 + cl] = v;
    }
    __syncthreads();

    // fused chunk carry: 32 threads, one per state in this n-slice, 64-step local scan
    if (tid < 32) {
        int b = m0 >> 9, ch = (m0 >> 6) & 7;
        int n = (n0 >> 1) + tid;
        float lre = lam[2*n], lim = lam[2*n+1];
        float hr = 0.f, hm = 0.f;
        const float2* L2 = (const float2*)smem;   // [64][32] float2
        float2 pf[8];
#pragma unroll
        for (int p = 0; p < 8; ++p) pf[p] = L2[p*32 + tid];
        for (int s0 = 0; s0 < 64; s0 += 8) {
#pragma unroll
            for (int p = 0; p < 8; ++p) {
                int s = s0 + p;
                float ur = pf[p].x, ui = pf[p].y;
                if (s + 8 < 64) pf[p] = L2[(s + 8)*32 + tid];
                float nr = fmaf(lre, hr, fmaf(-lim, hm, ur));
                float nm = fmaf(lre, hm, fmaf( lim, hr, ui));
                hr = nr; hm = nm;
            }
        }
        carry[(size_t)(b*8 + ch)*STATE + n] = make_float2(hr, hm);
    }
}

// ---------------- scan emit: prefix from carries, emit Z splits ----------------
__global__ __launch_bounds__(64)
void scan_emit(const float* __restrict__ Uf,
               u16* __restrict__ Z1, u16* __restrict__ Z2, u16* __restrict__ Z3,
               const float* __restrict__ lam, const float* __restrict__ lam64,
               const float2* __restrict__ carry,
               const float2* __restrict__ HcIn, float2* __restrict__ HcOut) {
    int bx = blockIdx.x;
    int b = bx / 48, rem = bx % 48, g = rem >> 3, c = rem & 7;
    int n = g*64 + threadIdx.x;
    float lre = lam[2*n], lim = lam[2*n+1];
    float p64r = lam64[2*n], p64i = lam64[2*n+1];
    float2 h = HcIn[(size_t)b*STATE + n];
    for (int j = 0; j < c; ++j) {
        float2 cj = carry[(size_t)(b*8 + j)*STATE + n];
        float nr = fmaf(p64r, h.x, fmaf(-p64i, h.y, cj.x));
        float ni = fmaf(p64r, h.y, fmaf( p64i, h.x, cj.y));
        h.x = nr; h.y = ni;
    }
    const float2* U2 = (const float2*)Uf + ((size_t)(b*SEQ + c*64))*STATE + n;
    size_t zb = (size_t)(b*SEQ + c*64)*NJ + 2*n;
    float2 buf[16];
#pragma unroll
    for (int p = 0; p < 16; ++p) buf[p] = U2[(size_t)p*STATE];
    for (int s0 = 0; s0 < 64; s0 += 16) {
#pragma unroll
        for (int p = 0; p < 16; ++p) {
            int s = s0 + p;
            float ur = buf[p].x, ui = buf[p].y;
            if (s + 16 < 64) buf[p] = U2[(size_t)(s+16)*STATE];
            float nr = fmaf(lre, h.x, fmaf(-lim, h.y, ur));
            float ni = fmaf(lre, h.y, fmaf( lim, h.x, ui));
            h.x = nr; h.y = ni;
            u16 a1,a2,a3, c1,c2,c3;
            split3(nr, a1,a2,a3);
            split3(ni, c1,c2,c3);
            size_t zo = zb + (size_t)s*NJ;
            ushort2 t;
            t.x = a1; t.y = c1; *(ushort2*)(Z1 + zo) = t;
            t.x = a2; t.y = c2; *(ushort2*)(Z2 + zo) = t;
            t.x = a3; t.y = c3; *(ushort2*)(Z3 + zo) = t;
        }
    }
    if (c == 7) HcOut[(size_t)b*STATE + n] = h;
}

// ---------------- GEMM2: z=8 uniform 128-K split; 128x64 tile; B in regs ------
// z 0..5: Z planes k-slice [z*128, z*128+128) vs WC; z 6..7: X planes vs WD.
struct G2P { const u16* Z[3]; const u16* X[3]; const u16* WC; const u16* WD; float* P; };

__global__ __launch_bounds__(256, 2)
void gemm2_k(G2P g) {
    __shared__ __align__(16) char smem[49152];   // 2 x 24KB (A dbuf)
    const int tid = threadIdx.x, lane = tid & 63, w = tid >> 6;
    const int wr = w & 1, wc = w >> 1;
    const int m0 = blockIdx.x*128, n0 = blockIdx.y*64;
    const int z = blockIdx.z;
    const int hi5 = lane >> 5, lo5 = lane & 31;
    const int c32 = (n0 >> 5) + wc;

    const u16* Ap[3]; const u16* Bp; int sA, kg0, t32b, NT32; size_t pBs;
    if (z < 6) {
        Ap[0]=g.Z[0]; Ap[1]=g.Z[1]; Ap[2]=g.Z[2];
        sA = NJ; kg0 = z*128; Bp = g.WC; pBs = PS_WC; t32b = z*4; NT32 = 24;
    } else {
        Ap[0]=g.X[0]; Ap[1]=g.X[1]; Ap[2]=g.X[2];
        sA = IN_CH; kg0 = (z - 6)*128; Bp = g.WD; pBs = PS_WD; t32b = (z - 6)*4; NT32 = 8;
    }

    f32x16 acc[2];
#pragma unroll
    for (int f = 0; f < 2; ++f)
#pragma unroll
        for (int i = 0; i < 16; ++i) acc[f][i] = 0.f;

    // B fragments in registers (whole 128-K slice), coalesced fragment-order loads
    bf16x8 bwin[3][4][2];
#pragma unroll
    for (int p = 0; p < 3; ++p)
#pragma unroll
        for (int t = 0; t < 4; ++t)
#pragma unroll
            for (int h = 0; h < 2; ++h)
                bwin[p][t][h] = *(const bf16x8*)(Bp + (size_t)p*pBs
                    + ((((size_t)(c32*NT32 + t32b + t)*2 + h)*2 + hi5) << 8) + lo5*8);

    auto stageA = [&](int t, int buf) {
        int kg = kg0 + t*32;
        char* L = smem + buf*24576;
#pragma unroll
        for (int r = 0; r < 6; ++r) {            // 1536 chunks of 16B
            int q = tid + r*256;
            int p = q >> 9, c = q & 511, o = c >> 7, row = c & 127;
            gload_lds16(Ap[p] + (size_t)(m0 + row)*sA + kg + o*8,
                        L + (size_t)q*16);
        }
    };

    stageA(0, 0);
    __syncthreads();
    int cur = 0;
#pragma unroll
    for (int t = 0; t < 4; ++t) {
        if (t + 1 < 4) stageA(t + 1, cur ^ 1);
        const char* L = smem + cur*24576;
        bf16x8 av[3][2][2];
#pragma unroll
        for (int p = 0; p < 3; ++p)
#pragma unroll
            for (int f = 0; f < 2; ++f)
#pragma unroll
                for (int h = 0; h < 2; ++h)
                    av[p][f][h] = *(const bf16x8*)(L + p*8192 + (2*h + hi5)*2048
                                                   + (wr*64 + f*32 + lo5)*16);
#pragma unroll
        for (int t6 = 0; t6 < 6; ++t6)
#pragma unroll
            for (int f = 0; f < 2; ++f)
#pragma unroll
                for (int h = 0; h < 2; ++h)
                    acc[f] = __builtin_amdgcn_mfma_f32_32x32x16_bf16(
                        av[cPI[t6]][f][h], bwin[cPJ[t6]][t][h], acc[f], 0, 0, 0);
        __syncthreads();
        cur ^= 1;
    }

    // epilogue: fp32 partial plane z
    float* P = g.P + (size_t)z*M_ROWS*IN_CH;
#pragma unroll
    for (int f = 0; f < 2; ++f)
#pragma unroll
        for (int reg = 0; reg < 16; ++reg) {
            int row = m0 + wr*64 + f*32 + (reg & 3) + 8*(reg >> 2) + 4*hi5;
            int col = n0 + wc*32 + lo5;
            P[(size_t)row*IN_CH + col] = acc[f][reg];
        }
}

// ---------------- combine 8 partials -> split3 planes + out row ----------------
__global__ __launch_bounds__(256)
void combine_k(const float* __restrict__ P,
               u16* __restrict__ O1, u16* __restrict__ O2, u16* __restrict__ O3,
               float* __restrict__ outp, int iter) {
    int idx = blockIdx.x*256 + threadIdx.x;     // 0..262143 (f32x4 units)
    const f32x4* P4 = (const f32x4*)P;
    f32x4 v = P4[idx];
#pragma unroll
    for (int z = 1; z < 8; ++z) v = v + P4[idx + (size_t)z*262144];
    ushort4 o1, o2, o3;
    u16 a,b,c;
    split3(v[0],a,b,c); o1.x=a; o2.x=b; o3.x=c;
    split3(v[1],a,b,c); o1.y=a; o2.y=b; o3.y=c;
    split3(v[2],a,b,c); o1.z=a; o2.z=b; o3.z=c;
    split3(v[3],a,b,c); o1.w=a; o2.w=b; o3.w=c;
    ((ushort4*)O1)[idx] = o1;
    ((ushort4*)O2)[idx] = o2;
    ((ushort4*)O3)[idx] = o3;
    int row = idx >> 6;
    if ((row & (SEQ-1)) == SEQ-1) {
        int col = (idx & 63) << 2;
        *(float4*)&outp[(size_t)((row >> 9)*OUT_SEQ + iter)*IN_CH + col] =
            make_float4(v[0], v[1], v[2], v[3]);
    }
}

// ---------------- launch ----------------
extern "C" void kernel_launch(void* const* d_in, const int* in_sizes, int n_in,
                              void* d_out, int out_size, void* d_ws, size_t ws_size,
                              hipStream_t stream) {
    const float* x_in      = (const float*)d_in[0];
    const float* nu_log    = (const float*)d_in[1];
    const float* theta_log = (const float*)d_in[2];
    const float* gamma_log = (const float*)d_in[3];
    const float* B_re      = (const float*)d_in[4];
    const float* B_im      = (const float*)d_in[5];
    const float* C_re      = (const float*)d_in[6];
    const float* C_im      = (const float*)d_in[7];
    const float* D         = (const float*)d_in[8];
    float* out = (float*)d_out;

    char* ws = (char*)d_ws;
    float* U   = (float*)(ws + B_U);
    u16* Z1 = (u16*)(ws + B_Z);
    u16* Z2 = Z1 + (size_t)M_ROWS*NJ;
    u16* Z3 = Z2 + (size_t)M_ROWS*NJ;
    u16* XA1 = (u16*)(ws + B_XA);
    u16* XA2 = XA1 + (size_t)M_ROWS*IN_CH;
    u16* XA3 = XA2 + (size_t)M_ROWS*IN_CH;
    u16* XB1 = (u16*)(ws + B_XB);
    u16* XB2 = XB1 + (size_t)M_ROWS*IN_CH;
    u16* XB3 = XB2 + (size_t)M_ROWS*IN_CH;
    u16* WB  = (u16*)(ws + B_WB);
    u16* WCt = (u16*)(ws + B_WC);
    u16* WDt = (u16*)(ws + B_WD);
    float* lam   = (float*)(ws + B_LAM);
    float* lam64 = lam + 768;
    float2* Hc0  = (float2*)(ws + B_HC);
    float2* Hc1  = Hc0 + (size_t)B_SZ*STATE;
    float2* carry = (float2*)(ws + B_CAR);

    prep_lam_hc<<<1, 384, 0, stream>>>(nu_log, theta_log, lam, lam64, (float*)Hc0);
    prep_wb<<<PS_WB/256, 256, 0, stream>>>(B_re, B_im, gamma_log, WB);
    prep_wcd<<<(PS_WC + PS_WD)/256, 256, 0, stream>>>(C_re, C_im, D, WCt, WDt);
    prep_x<<<(M_ROWS*IN_CH)/256, 256, 0, stream>>>(x_in, XA1, XA2, XA3);

    for (int it = 0; it < OUT_SEQ; ++it) {
        u16* Xc[3]; u16* Xn[3];
        if (it & 1) { Xc[0]=XB1; Xc[1]=XB2; Xc[2]=XB3; Xn[0]=XA1; Xn[1]=XA2; Xn[2]=XA3; }
        else        { Xc[0]=XA1; Xc[1]=XA2; Xc[2]=XA3; Xn[0]=XB1; Xn[1]=XB2; Xn[2]=XB3; }
        float2* Hin  = (it & 1) ? Hc1 : Hc0;
        float2* Hout = (it & 1) ? Hc0 : Hc1;

        // GEMM1 + fused chunk-carries
        G1P g1;
        for (int p = 0; p < 3; ++p) g1.A[p] = Xc[p];
        gemm1_k<<<dim3(M_ROWS/64, NJ/64), 256, 0, stream>>>(g1, WB, U, lam, carry);

        // scan emit (prefix from carries)
        scan_emit<<<384, 64, 0, stream>>>(U, Z1, Z2, Z3, lam, lam64, carry, Hin, Hout);

        // GEMM2: z=8 uniform 128-K split partials
        G2P g2;
        g2.Z[0]=Z1; g2.Z[1]=Z2; g2.Z[2]=Z3;
        g2.X[0]=Xc[0]; g2.X[1]=Xc[1]; g2.X[2]=Xc[2];
        g2.WC = WCt; g2.WD = WDt; g2.P = U;
        gemm2_k<<<dim3(M_ROWS/128, IN_CH/64, 8), 256, 0, stream>>>(g2);

        // combine partials -> Xn splits + out row
        combine_k<<<1024, 256, 0, stream>>>(U, Xn[0], Xn[1], Xn[2], out, it);
    }
}